// Round 4
// baseline (1329.787 us; speedup 1.0000x reference)
//
#include <hip/hip_runtime.h>

// Problem constants
#define VSZ   32000
#define HSZ   512
#define LSZ   4
#define BSZ   32
#define TSZ   51            // MAX_LEN + 1
#define OUT_LOGITS 52224000 // B*T*V
#define MPAD  1664          // T*B=1632 padded to 26*64

// ws layout (float offsets)
// XHB: ping-pong x|h state as bf16 hi/lo planes:
//   ushort [2 buf][4 layer][128 k8][32 b][2 plane*8] ; k = k8*8 + slot,
//   k<512 = x-half, k>=512 = h-half; plane0 = hi bf16, plane1 = lo bf16.
//   524288 ushorts = 262144 float-slots (same footprint as old fp32 XH).
#define WS_XH    0          // 262144 float-slots
#define WS_HTOP  262144     // bf16 [1664][512] = 851968 ushorts = 425984 float-slots
#define WS_WB    688128     // bf16 [32000][512] = 8192000 float-slots
#define WS_CNT   8880128    // u32 counters: [4][64] stage counters + [256] init

typedef __attribute__((ext_vector_type(8))) short bf16x8;
typedef __attribute__((ext_vector_type(4))) float f32x4;

static __device__ __forceinline__ unsigned short f2bf(float f) {
    unsigned int u = __float_as_uint(f);
    unsigned int r = (u + 0x7FFFu + ((u >> 16) & 1u)) >> 16;   // RNE
    return (unsigned short)r;
}

// fp32 -> (hi, lo) bf16 pair via truncation split; packs two scalars into one u32
// (element0 in low16). W ~ Whi + Wlo captures ~17 mantissa bits.
static __device__ __forceinline__ void split2(float f0, float f1,
                                              unsigned int& hi, unsigned int& lo) {
    unsigned int u0 = __float_as_uint(f0), u1 = __float_as_uint(f1);
    unsigned int h0 = u0 & 0xffff0000u, h1 = u1 & 0xffff0000u;
    hi = (u0 >> 16) | h1;
    float d0 = f0 - __uint_as_float(h0);
    float d1 = f1 - __uint_as_float(h1);
    lo = (__float_as_uint(d0) >> 16) | (__float_as_uint(d1) & 0xffff0000u);
}

static __device__ __forceinline__ unsigned int ld_cnt(unsigned int* p) {
    return __hip_atomic_load(p, __ATOMIC_RELAXED, __HIP_MEMORY_SCOPE_AGENT);
}

// producer-side split store: writes hi bf16 at base[0], lo bf16 at base[8]
// (agent-scope write-through so cross-XCD consumers see it after acquire-fence)
static __device__ __forceinline__ void st_split(unsigned short* base, float v) {
    unsigned int u = __float_as_uint(v);
    unsigned int h = u & 0xffff0000u;
    float d = v - __uint_as_float(h);
    __hip_atomic_store(base, (unsigned short)(u >> 16),
                       __ATOMIC_RELAXED, __HIP_MEMORY_SCOPE_AGENT);
    __hip_atomic_store(base + 8, (unsigned short)(__float_as_uint(d) >> 16),
                       __ATOMIC_RELAXED, __HIP_MEMORY_SCOPE_AGENT);
}

// XHB ushort index: [buf][layer][k8][b][16]  (hi at +0..7, lo at +8..15)
#define XHB_IDX(buf, layer, k8, b) (((((buf)*4 + (layer))*128 + (k8))*32 + (b))*16)

// ---------------- Kernel C: W_out fp32 -> bf16 ----------------
__global__ __launch_bounds__(256) void convw_kernel(const float* __restrict__ W,
                                                    unsigned short* __restrict__ WB) {
    const int n4 = VSZ * HSZ / 4;  // 4,096,000 float4s
    for (int i = blockIdx.x * 256 + threadIdx.x; i < n4; i += gridDim.x * 256) {
        float4 f = ((const float4*)W)[i];
        ushort4 o;
        o.x = f2bf(f.x); o.y = f2bf(f.y); o.z = f2bf(f.z); o.w = f2bf(f.w);
        ((ushort4*)WB)[i] = o;
    }
}

// ---------------- Kernel A: MFMA point-to-point pipelined LSTM ----------------
// 256 blocks x 512 threads (8 waves), cooperative launch for co-residency ONLY.
// Block (l = blockIdx>>6, jt = blockIdx&63): 32-row (8 j x 4 gate) x 32-b gate
// tile per stage via bf16 MFMA, 3-pass hi/lo:
//   gates = Whi*Xhi + Wlo*Xhi + Whi*Xlo   (fp32 accumulate)
// Wave w: m-tile (w>>1)&1, n-tile w&1, K-half w>>2. Weights = VGPR A-frags
// (preloaded once). X comes PRE-SPLIT from XHB (producer-side split) so the
// inner loop is pure {2 x dwordx4 load, 3 MFMA} per K32 step.
__global__ __launch_bounds__(512, 2) void lstm_kernel(
    const float* __restrict__ dec_h, const float* __restrict__ dec_c,
    const int* __restrict__ target, const float* __restrict__ emb,
    const float* __restrict__ Wih, const float* __restrict__ Whh,
    const float* __restrict__ bih, const float* __restrict__ bhh,
    float* __restrict__ ws, float* __restrict__ out)
{
    __shared__ f32x4 red[4][64];   // cross-wave K-reduce buffer (4 KB)

    unsigned short* XHB = (unsigned short*)(ws + WS_XH);
    unsigned short* HTOP = (unsigned short*)(ws + WS_HTOP);
    unsigned int* cnt = (unsigned int*)(ws + WS_CNT);   // [4][64] + [256]=init

    const int tid  = threadIdx.x;
    const int lane = tid & 63;
    const int w    = tid >> 6;           // wave 0..7
    const int mt   = (w >> 1) & 1;       // m-tile (rows 0-15 / 16-31)
    const int nt   = w & 1;              // n-tile (b 0-15 / 16-31)
    const int ks   = w >> 2;             // K-half: 0 = x (W_ih), 1 = h (W_hh)
    const int mi   = lane & 15;
    const int kg   = lane >> 4;          // k-group within fragment
    const int l    = blockIdx.x >> 6;    // 0..3
    const int jt   = blockIdx.x & 63;    // 0..63

    // ---- cell ownership (meaningful for waves 0..3) ----
    const int jc = jt * 8 + mt * 4 + kg;   // this lane's j
    const int bc = nt * 16 + mi;           // this lane's b

    const int rjc = l * 2048 + jc;
    const float bias0 = bih[rjc]        + bhh[rjc];
    const float bias1 = bih[rjc + 512]  + bhh[rjc + 512];
    const float bias2 = bih[rjc + 1024] + bhh[rjc + 1024];
    const float bias3 = bih[rjc + 1536] + bhh[rjc + 1536];

    float c_reg = dec_c[(l * 32 + bc) * 512 + jc];

    // ---- one-time: preload A-fragments (weights) into VGPRs, hi/lo bf16 ----
    bf16x8 wa_hi[16], wa_lo[16];
    {
        const int g_a   = mi & 3;
        const int jl_a  = mt * 4 + (mi >> 2);
        const int row_a = l * 2048 + g_a * 512 + jt * 8 + jl_a;
        const float* wrow = (ks ? Whh : Wih) + (size_t)row_a * 512;
        #pragma unroll
        for (int kk = 0; kk < 16; ++kk) {
            float4 v0 = *(const float4*)(wrow + kk * 32 + kg * 8);
            float4 v1 = *(const float4*)(wrow + kk * 32 + kg * 8 + 4);
            union { unsigned int u[4]; bf16x8 v; } H, L;
            split2(v0.x, v0.y, H.u[0], L.u[0]);
            split2(v0.z, v0.w, H.u[1], L.u[1]);
            split2(v1.x, v1.y, H.u[2], L.u[2]);
            split2(v1.z, v1.w, H.u[3], L.u[3]);
            wa_hi[kk] = H.v; wa_lo[kk] = L.v;
        }
    }

    // ---- init: XHB[1][0][x] = emb[SOS], XHB[(l+1)&1][l][h] = dec_h ----
    {
        const int gid = blockIdx.x * 512 + tid;   // 0..131071
        if (gid < 16384) {
            int k = gid >> 5, bb = gid & 31;
            st_split(XHB + XHB_IDX(1, 0, k >> 3, bb) + (k & 7), emb[k]);  // SOS == 0
        }
        if (gid < 65536) {
            int l2 = gid >> 14;
            int rem = gid & 16383;
            int j2 = rem >> 5, b2 = rem & 31;
            st_split(XHB + XHB_IDX((l2 + 1) & 1, l2, 64 + (j2 >> 3), b2) + (j2 & 7),
                     dec_h[(l2 * 32 + b2) * 512 + j2]);
        }
    }
    // init barrier
    __syncthreads();
    if (tid == 0) {
        __builtin_amdgcn_fence(__ATOMIC_RELEASE, "agent");
        __hip_atomic_fetch_add(&cnt[256], 1u, __ATOMIC_RELAXED, __HIP_MEMORY_SCOPE_AGENT);
        while (ld_cnt(&cnt[256]) < 256u) { __builtin_amdgcn_s_sleep(1); }
        __builtin_amdgcn_fence(__ATOMIC_ACQUIRE, "agent");
    }
    __syncthreads();

    for (int s = 0; s < 54; ++s) {
        const int pp = (s + 1) & 1;   // read parity
        const int pw = s & 1;         // write parity
        const int t  = s - l;

        // ---- WAIT: batched parallel poll of up to 3 dependency counters ----
        if (s > 0 && tid == 0) {
            unsigned int* c0 = &cnt[l * 64 + s - 1];
            unsigned int* c1 = (l > 0) ? &cnt[(l - 1) * 64 + s - 1] : c0;
            unsigned int* c2 = (l < 3) ? &cnt[(l + 1) * 64 + s - 1] : c0;
            for (;;) {
                unsigned int a = ld_cnt(c0);
                unsigned int b2 = ld_cnt(c1);
                unsigned int c3 = ld_cnt(c2);
                if (a >= 64u && b2 >= 64u && c3 >= 64u) break;
            }
            __builtin_amdgcn_fence(__ATOMIC_ACQUIRE, "agent");
        }
        __syncthreads();

        // pre-pass: layer-0 blocks build layer-0 x (token t_next = s+1)
        if (l == 0 && s < 50 && tid < 256) {
            int e = jt * 256 + tid;               // 0..16383 across 64 l==0 blocks
            int k = e >> 5, bb = e & 31;
            int tok = target[bb * TSZ + s];
            st_split(XHB + XHB_IDX(pw, 0, k >> 3, bb) + (k & 7),
                     emb[tok * 512 + k]);
        }

        if (t >= 0 && t <= 50) {
            // B-frag: lane needs X[b = bc][k = ks*512 + kk*32 + kg*8 ..+8)
            // pre-split planes: hi at +0..7, lo at +8..15
            const unsigned short* xb = XHB + XHB_IDX(pp, l, ks * 64 + kg, bc);

            f32x4 acc_a = {0.f, 0.f, 0.f, 0.f};   // Whi*Xhi chain
            f32x4 acc_b = {0.f, 0.f, 0.f, 0.f};   // Wlo*Xhi + Whi*Xlo chain
            #pragma unroll
            for (int kk = 0; kk < 16; ++kk) {
                bf16x8 xhi = *(const bf16x8*)(xb + kk * 2048);
                bf16x8 xlo = *(const bf16x8*)(xb + kk * 2048 + 8);
                acc_a = __builtin_amdgcn_mfma_f32_16x16x32_bf16(wa_hi[kk], xhi, acc_a, 0, 0, 0);
                acc_b = __builtin_amdgcn_mfma_f32_16x16x32_bf16(wa_lo[kk], xhi, acc_b, 0, 0, 0);
                acc_b = __builtin_amdgcn_mfma_f32_16x16x32_bf16(wa_hi[kk], xlo, acc_b, 0, 0, 0);
            }
            f32x4 acc = acc_a + acc_b;

            // cross-wave K-reduce: (w, w+4) share the same (mt, nt).
            // (red WAR vs previous stage is covered by ARRIVE+WAIT barriers.)
            if (w >= 4) red[w - 4][lane] = acc;
            __syncthreads();
            if (w < 4) {
                f32x4 rp = red[w][lane];
                float pi = acc[0] + rp[0] + bias0;
                float pf = acc[1] + rp[1] + bias1;
                float pg = acc[2] + rp[2] + bias2;
                float po = acc[3] + rp[3] + bias3;
                float ig = 1.f / (1.f + expf(-pi));
                float fg = 1.f / (1.f + expf(-pf));
                float gg = tanhf(pg);
                float og = 1.f / (1.f + expf(-po));
                float cn = fg * c_reg + ig * gg;
                float hn = og * tanhf(cn);                  // pre-clamp h
                c_reg     = fminf(fmaxf(cn, -50.f), 50.f);
                float hcl = fminf(fmaxf(hn, -50.f), 50.f);

                // recurrent h input for own layer at t+1 (clipped)
                st_split(XHB + XHB_IDX(pw, l, 64 + (jc >> 3), bc) + (jc & 7), hcl);
                if (l < 3)   // x input for layer l+1 (pre-clamp)
                    st_split(XHB + XHB_IDX(pw, l + 1, jc >> 3, bc) + (jc & 7), hn);
                if (l == 3)
                    HTOP[((t * 32 + bc) << 9) + jc] = f2bf(hn);   // pre-clamp top h
                if (t == 50)
                    out[OUT_LOGITS + ((l * 32 + bc) << 9) + jc] = hcl;   // h_fin
            }
        }

        // ---- ARRIVE ----
        __syncthreads();
        if (tid == 0) {
            __builtin_amdgcn_fence(__ATOMIC_RELEASE, "agent");
            __hip_atomic_fetch_add(&cnt[l * 64 + s], 1u, __ATOMIC_RELAXED,
                                   __HIP_MEMORY_SCOPE_AGENT);
        }
    }
}

// ---------------- Kernel B: bf16 MFMA projection (gemm_bt) ----------------
// C[m, v] = sum_k HTOP[m,k] * WB[v,k] + b_out[v];  m = t*32 + b  ->  out[(b*51+t)*V + v]
__global__ __launch_bounds__(256) void proj_kernel(
    const unsigned short* __restrict__ A, const unsigned short* __restrict__ Bm,
    const float* __restrict__ bout, float* __restrict__ out)
{
    __shared__ unsigned short As[64 * 40];
    __shared__ unsigned short Bs[64 * 40];
    const int tid = threadIdx.x;
    const int bn = blockIdx.x;   // 0..499
    const int bm = blockIdx.y;   // 0..25
    const int w = tid >> 6, lane = tid & 63;
    const int lr = lane & 15, lq = lane >> 4;

    f32x4 acc0 = {0.f, 0.f, 0.f, 0.f};
    f32x4 acc1 = {0.f, 0.f, 0.f, 0.f};
    f32x4 acc2 = {0.f, 0.f, 0.f, 0.f};
    f32x4 acc3 = {0.f, 0.f, 0.f, 0.f};

    const int r = tid >> 2, c8 = (tid & 3) * 8;
    const unsigned short* Ag = A + (bm * 64 + r) * HSZ + c8;
    const unsigned short* Bg = Bm + (size_t)(bn * 64 + r) * HSZ + c8;

    for (int kt = 0; kt < 16; ++kt) {
        *(uint4*)&As[r * 40 + c8] = *(const uint4*)(Ag + kt * 32);
        *(uint4*)&Bs[r * 40 + c8] = *(const uint4*)(Bg + kt * 32);
        __syncthreads();
        bf16x8 af = *(const bf16x8*)&As[(w * 16 + lr) * 40 + lq * 8];
        bf16x8 b0 = *(const bf16x8*)&Bs[(0 * 16 + lr) * 40 + lq * 8];
        bf16x8 b1 = *(const bf16x8*)&Bs[(1 * 16 + lr) * 40 + lq * 8];
        bf16x8 b2 = *(const bf16x8*)&Bs[(2 * 16 + lr) * 40 + lq * 8];
        bf16x8 b3 = *(const bf16x8*)&Bs[(3 * 16 + lr) * 40 + lq * 8];
        acc0 = __builtin_amdgcn_mfma_f32_16x16x32_bf16(af, b0, acc0, 0, 0, 0);
        acc1 = __builtin_amdgcn_mfma_f32_16x16x32_bf16(af, b1, acc1, 0, 0, 0);
        acc2 = __builtin_amdgcn_mfma_f32_16x16x32_bf16(af, b2, acc2, 0, 0, 0);
        acc3 = __builtin_amdgcn_mfma_f32_16x16x32_bf16(af, b3, acc3, 0, 0, 0);
        __syncthreads();
    }

    f32x4 accs[4] = {acc0, acc1, acc2, acc3};
    #pragma unroll
    for (int nt = 0; nt < 4; ++nt) {
        const int v = bn * 64 + nt * 16 + lr;
        const float bo = bout[v];
        #pragma unroll
        for (int reg = 0; reg < 4; ++reg) {
            const int m = bm * 64 + w * 16 + lq * 4 + reg;
            if (m < TSZ * BSZ) {
                const int tt = m >> 5, bb = m & 31;
                out[(size_t)(bb * TSZ + tt) * VSZ + v] = accs[nt][reg] + bo;
            }
        }
    }
}

extern "C" void kernel_launch(void* const* d_in, const int* in_sizes, int n_in,
                              void* d_out, int out_size, void* d_ws, size_t ws_size,
                              hipStream_t stream) {
    const float* dec_h = (const float*)d_in[1];
    const float* dec_c = (const float*)d_in[2];
    const int*   tgt   = (const int*)d_in[3];
    const float* emb   = (const float*)d_in[4];
    const float* Wih   = (const float*)d_in[5];
    const float* Whh   = (const float*)d_in[6];
    const float* bihp  = (const float*)d_in[7];
    const float* bhhp  = (const float*)d_in[8];
    const float* Wout  = (const float*)d_in[9];
    const float* bout  = (const float*)d_in[10];
    float* out = (float*)d_out;
    float* ws  = (float*)d_ws;

    unsigned short* HTOP = (unsigned short*)(ws + WS_HTOP);
    unsigned short* WB   = (unsigned short*)(ws + WS_WB);

    // zero the p2p sync counters (graph-capture safe)
    hipMemsetAsync(ws + WS_CNT, 0, 1040, stream);

    // W_out -> bf16 (independent of the recurrence)
    convw_kernel<<<4096, 256, 0, stream>>>(Wout, WB);

    // MFMA point-to-point pipelined LSTM (cooperative launch for co-residency)
    void* args[] = { (void*)&dec_h, (void*)&dec_c, (void*)&tgt, (void*)&emb,
                     (void*)&Wih, (void*)&Whh, (void*)&bihp, (void*)&bhhp,
                     (void*)&ws, (void*)&out };
    hipLaunchCooperativeKernel(reinterpret_cast<void*>(lstm_kernel),
                               dim3(256), dim3(512), args, 0, stream);

    // batched output projection
    proj_kernel<<<dim3(VSZ / 64, MPAD / 64), 256, 0, stream>>>(HTOP, WB, bout, out);
}

// Round 6
// 1226.200 us; speedup vs baseline: 1.0845x; 1.0845x over previous
//
#include <hip/hip_runtime.h>

// Problem constants
#define VSZ   32000
#define HSZ   512
#define LSZ   4
#define BSZ   32
#define TSZ   51            // MAX_LEN + 1
#define OUT_LOGITS 52224000 // B*T*V
#define MPAD  1664          // T*B=1632 padded to 26*64

// ws layout (float offsets)
// XH: 4-slot ring of x|h state, fp32 [4 slot][4 layer][K/4=256][32 b][4]
//     (k<512 = x-half, k>=512 = h-half). Stage s writes slot s&3, reads (s+3)&3.
#define WS_XH    0          // 4*131072 = 524288 floats
#define WS_X0    524288     // layer-0 input stream [51 t][128 k4][32 b][4] = 835584 floats
#define WS_HTOP  1359872    // bf16 [1664][512] = 851968 ushorts = 425984 float-slots
#define WS_WB    1785856    // bf16 [32000][512] = 8192000 float-slots
#define WS_CNT   9977856    // u32 counters: [4][64] stage counters + [256] init

typedef __attribute__((ext_vector_type(8))) short bf16x8;
typedef __attribute__((ext_vector_type(4))) float f32x4;

static __device__ __forceinline__ unsigned short f2bf(float f) {
    unsigned int u = __float_as_uint(f);
    unsigned int r = (u + 0x7FFFu + ((u >> 16) & 1u)) >> 16;   // RNE
    return (unsigned short)r;
}

// fp32 -> (hi, lo) bf16 pair via truncation split; packs two scalars into one u32
// (element0 in low16). W ~ Whi + Wlo captures ~17 mantissa bits.
static __device__ __forceinline__ void split2(float f0, float f1,
                                              unsigned int& hi, unsigned int& lo) {
    unsigned int u0 = __float_as_uint(f0), u1 = __float_as_uint(f1);
    unsigned int h0 = u0 & 0xffff0000u, h1 = u1 & 0xffff0000u;
    hi = (u0 >> 16) | h1;
    float d0 = f0 - __uint_as_float(h0);
    float d1 = f1 - __uint_as_float(h1);
    lo = (__float_as_uint(d0) >> 16) | (__float_as_uint(d1) & 0xffff0000u);
}

// agent-scope (device-coherent) state store / counter load
static __device__ __forceinline__ void st_xh(float* p, float v) {
    __hip_atomic_store(p, v, __ATOMIC_RELAXED, __HIP_MEMORY_SCOPE_AGENT);
}
static __device__ __forceinline__ unsigned int ld_cnt(unsigned int* p) {
    return __hip_atomic_load(p, __ATOMIC_RELAXED, __HIP_MEMORY_SCOPE_AGENT);
}

// ---------------- Kernel C: W_out fp32 -> bf16 ----------------
__global__ __launch_bounds__(256) void convw_kernel(const float* __restrict__ W,
                                                    unsigned short* __restrict__ WB) {
    const int n4 = VSZ * HSZ / 4;  // 4,096,000 float4s
    for (int i = blockIdx.x * 256 + threadIdx.x; i < n4; i += gridDim.x * 256) {
        float4 f = ((const float4*)W)[i];
        ushort4 o;
        o.x = f2bf(f.x); o.y = f2bf(f.y); o.z = f2bf(f.z); o.w = f2bf(f.w);
        ((ushort4*)WB)[i] = o;
    }
}

// ---------------- Kernel A: MFMA ring-buffered p2p pipelined LSTM ----------------
// 256 blocks x 512 threads (8 waves), cooperative launch for co-residency ONLY.
// Block (l = blockIdx>>6, jt = blockIdx&63): 32-row (8 j x 4 gate) x 32-b gate
// tile per stage via bf16 MFMA, 3-pass hi/lo (fp32 XH, consumer-side split —
// round-3 format; round-4's producer-split 2B stores regressed WRITE 3.5x).
// Ring-4 XH: stage s writes slot s&3, reads slot (s+3)&3. Waits per stage:
//   cnt[l][s-1]   (own h, true dep; also covers own-slot WAR)
//   cnt[l-1][s-1] (x producer, true dep)
//   cnt[l+1][s-3] (WAR on slot s&3's l+1 x-region — never binding in steady state)
// Layer-0 x comes from the precomputed read-only X0TAB (teacher forcing), so
// there is no per-stage prefill and layer 0 has no x producer.
__global__ __launch_bounds__(512, 2) void lstm_kernel(
    const float* __restrict__ dec_h, const float* __restrict__ dec_c,
    const int* __restrict__ target, const float* __restrict__ emb,
    const float* __restrict__ Wih, const float* __restrict__ Whh,
    const float* __restrict__ bih, const float* __restrict__ bhh,
    float* __restrict__ ws, float* __restrict__ out)
{
    __shared__ f32x4 red[4][64];   // cross-wave K-reduce buffer (4 KB)

    float* XH = ws + WS_XH;                        // [4][4][256][32][4]
    float* X0 = ws + WS_X0;                        // [51][128][32][4]
    unsigned short* HTOP = (unsigned short*)(ws + WS_HTOP);
    unsigned int* cnt = (unsigned int*)(ws + WS_CNT);   // [4][64] + [256]=init

    const int tid  = threadIdx.x;
    const int lane = tid & 63;
    const int w    = tid >> 6;           // wave 0..7
    const int mt   = (w >> 1) & 1;       // m-tile (rows 0-15 / 16-31)
    const int nt   = w & 1;              // n-tile (b 0-15 / 16-31)
    const int ks   = w >> 2;             // K-half: 0 = x (W_ih), 1 = h (W_hh)
    const int mi   = lane & 15;
    const int kg   = lane >> 4;          // k-group within fragment
    const int l    = blockIdx.x >> 6;    // 0..3
    const int jt   = blockIdx.x & 63;    // 0..63

    // ---- cell ownership (meaningful for waves 0..3) ----
    const int jc = jt * 8 + mt * 4 + kg;   // this lane's j
    const int bc = nt * 16 + mi;           // this lane's b

    const int rjc = l * 2048 + jc;
    const float bias0 = bih[rjc]        + bhh[rjc];
    const float bias1 = bih[rjc + 512]  + bhh[rjc + 512];
    const float bias2 = bih[rjc + 1024] + bhh[rjc + 1024];
    const float bias3 = bih[rjc + 1536] + bhh[rjc + 1536];

    float c_reg = dec_c[(l * 32 + bc) * 512 + jc];

    // ---- one-time: preload A-fragments (weights) into VGPRs, hi/lo bf16 ----
    bf16x8 wa_hi[16], wa_lo[16];
    {
        const int g_a   = mi & 3;
        const int jl_a  = mt * 4 + (mi >> 2);
        const int row_a = l * 2048 + g_a * 512 + jt * 8 + jl_a;
        const float* wrow = (ks ? Whh : Wih) + (size_t)row_a * 512;
        #pragma unroll
        for (int kk = 0; kk < 16; ++kk) {
            float4 v0 = *(const float4*)(wrow + kk * 32 + kg * 8);
            float4 v1 = *(const float4*)(wrow + kk * 32 + kg * 8 + 4);
            union { unsigned int u[4]; bf16x8 v; } H, L;
            split2(v0.x, v0.y, H.u[0], L.u[0]);
            split2(v0.z, v0.w, H.u[1], L.u[1]);
            split2(v1.x, v1.y, H.u[2], L.u[2]);
            split2(v1.z, v1.w, H.u[3], L.u[3]);
            wa_hi[kk] = H.v; wa_lo[kk] = L.v;
        }
    }

    // ---- init ----
    {
        const int gid = blockIdx.x * 512 + tid;   // 0..131071
        // dec_h for layer l2 -> ring slot (l2+3)&3 (read at stage l2), h-half
        if (gid < 65536) {
            int l2 = gid >> 14;
            int rem = gid & 16383;
            int j2 = rem >> 5, b2 = rem & 31;
            st_xh(&XH[((l2 + 3) & 3) * 131072 + l2 * 32768 +
                      (128 + (j2 >> 2)) * 128 + b2 * 4 + (j2 & 3)],
                  dec_h[(l2 * 32 + b2) * 512 + j2]);
        }
        // layer-0 input stream: X0TAB[t][k][b] = emb[token(t,b)][k]
        // token(0,b)=SOS=0; token(t,b)=target[b][t-1]
        for (int idx = gid; idx < TSZ * 16384; idx += 131072) {
            int tt2 = idx >> 14;
            int rem = idx & 16383;
            int k = rem >> 5, bb = rem & 31;
            int tok = tt2 ? target[bb * TSZ + tt2 - 1] : 0;
            st_xh(&X0[tt2 * 16384 + (k >> 2) * 128 + bb * 4 + (k & 3)],
                  emb[tok * 512 + k]);
        }
    }
    // init barrier (covers A-frag preload + all init stores)
    __syncthreads();
    if (tid == 0) {
        __builtin_amdgcn_fence(__ATOMIC_RELEASE, "agent");
        __hip_atomic_fetch_add(&cnt[256], 1u, __ATOMIC_RELAXED, __HIP_MEMORY_SCOPE_AGENT);
        while (ld_cnt(&cnt[256]) < 256u) { __builtin_amdgcn_s_sleep(1); }
        __builtin_amdgcn_fence(__ATOMIC_ACQUIRE, "agent");
    }
    __syncthreads();

    for (int s = 0; s < 54; ++s) {
        const int rp = (s + 3) & 3;   // read slot
        const int wp = s & 3;         // write slot
        const int t  = s - l;

        // ---- WAIT: batched parallel poll of up to 3 dependency counters ----
        if (s > 0 && tid == 0) {
            unsigned int* c0 = &cnt[l * 64 + s - 1];
            unsigned int* c1 = (l > 0) ? &cnt[(l - 1) * 64 + s - 1] : c0;
            unsigned int* c2 = (l < 3 && s >= 3) ? &cnt[(l + 1) * 64 + s - 3] : c0;
            for (;;) {
                unsigned int a  = ld_cnt(c0);
                unsigned int b2 = ld_cnt(c1);
                unsigned int c3 = ld_cnt(c2);
                if (a >= 64u && b2 >= 64u && c3 >= 64u) break;
            }
            __builtin_amdgcn_fence(__ATOMIC_ACQUIRE, "agent");
        }
        __syncthreads();

        if (t >= 0 && t <= 50) {
            // B-frag source: lane needs X[b = bc][k = ks*512 + kk*32 + kg*8 ..+8)
            const float* xbase = (l == 0 && ks == 0)
                               ? (X0 + t * 16384)
                               : (XH + rp * 131072 + l * 32768 + ks * 16384);
            const f32x4* xb4 = (const f32x4*)xbase + kg * 64 + bc;

            f32x4 acc_a = {0.f, 0.f, 0.f, 0.f};   // Whi*Xhi chain
            f32x4 acc_b = {0.f, 0.f, 0.f, 0.f};   // Wlo*Xhi + Whi*Xlo chain
            #pragma unroll
            for (int kk = 0; kk < 16; ++kk) {
                f32x4 x0 = xb4[kk * 256];
                f32x4 x1 = xb4[kk * 256 + 32];
                union { unsigned int u[4]; bf16x8 v; } XHI, XLO;
                split2(x0.x, x0.y, XHI.u[0], XLO.u[0]);
                split2(x0.z, x0.w, XHI.u[1], XLO.u[1]);
                split2(x1.x, x1.y, XHI.u[2], XLO.u[2]);
                split2(x1.z, x1.w, XHI.u[3], XLO.u[3]);
                acc_a = __builtin_amdgcn_mfma_f32_16x16x32_bf16(wa_hi[kk], XHI.v, acc_a, 0, 0, 0);
                acc_b = __builtin_amdgcn_mfma_f32_16x16x32_bf16(wa_lo[kk], XHI.v, acc_b, 0, 0, 0);
                acc_b = __builtin_amdgcn_mfma_f32_16x16x32_bf16(wa_hi[kk], XLO.v, acc_b, 0, 0, 0);
            }
            f32x4 acc = acc_a + acc_b;

            // cross-wave K-reduce: (w, w+4) share the same (mt, nt).
            // (red WAR vs previous stage is covered by ARRIVE+WAIT barriers.)
            if (w >= 4) red[w - 4][lane] = acc;
            __syncthreads();
            if (w < 4) {
                f32x4 rp2 = red[w][lane];
                float pi = acc[0] + rp2[0] + bias0;
                float pf = acc[1] + rp2[1] + bias1;
                float pg = acc[2] + rp2[2] + bias2;
                float po = acc[3] + rp2[3] + bias3;
                float ig = 1.f / (1.f + expf(-pi));
                float fg = 1.f / (1.f + expf(-pf));
                float gg = tanhf(pg);
                float og = 1.f / (1.f + expf(-po));
                float cn = fg * c_reg + ig * gg;
                float hn = og * tanhf(cn);                  // pre-clamp h
                c_reg     = fminf(fmaxf(cn, -50.f), 50.f);
                float hcl = fminf(fmaxf(hn, -50.f), 50.f);

                // recurrent h input for own layer at t+1 (clipped)
                st_xh(&XH[wp * 131072 + l * 32768 + (128 + (jc >> 2)) * 128 + bc * 4 + (jc & 3)], hcl);
                if (l < 3)   // x input for layer l+1 (pre-clamp)
                    st_xh(&XH[wp * 131072 + (l + 1) * 32768 + (jc >> 2) * 128 + bc * 4 + (jc & 3)], hn);
                if (l == 3)
                    HTOP[((t * 32 + bc) << 9) + jc] = f2bf(hn);   // pre-clamp top h
                if (t == 50)
                    out[OUT_LOGITS + ((l * 32 + bc) << 9) + jc] = hcl;   // h_fin
            }
        }

        // ---- ARRIVE ----
        __syncthreads();
        if (tid == 0) {
            __builtin_amdgcn_fence(__ATOMIC_RELEASE, "agent");
            __hip_atomic_fetch_add(&cnt[l * 64 + s], 1u, __ATOMIC_RELAXED,
                                   __HIP_MEMORY_SCOPE_AGENT);
        }
    }
}

// ---------------- Kernel B: bf16 MFMA projection (gemm_bt) ----------------
// C[m, v] = sum_k HTOP[m,k] * WB[v,k] + b_out[v];  m = t*32 + b  ->  out[(b*51+t)*V + v]
__global__ __launch_bounds__(256) void proj_kernel(
    const unsigned short* __restrict__ A, const unsigned short* __restrict__ Bm,
    const float* __restrict__ bout, float* __restrict__ out)
{
    __shared__ unsigned short As[64 * 40];
    __shared__ unsigned short Bs[64 * 40];
    const int tid = threadIdx.x;
    const int bn = blockIdx.x;   // 0..499
    const int bm = blockIdx.y;   // 0..25
    const int w = tid >> 6, lane = tid & 63;
    const int lr = lane & 15, lq = lane >> 4;

    f32x4 acc0 = {0.f, 0.f, 0.f, 0.f};
    f32x4 acc1 = {0.f, 0.f, 0.f, 0.f};
    f32x4 acc2 = {0.f, 0.f, 0.f, 0.f};
    f32x4 acc3 = {0.f, 0.f, 0.f, 0.f};

    const int r = tid >> 2, c8 = (tid & 3) * 8;
    const unsigned short* Ag = A + (bm * 64 + r) * HSZ + c8;
    const unsigned short* Bg = Bm + (size_t)(bn * 64 + r) * HSZ + c8;

    for (int kt = 0; kt < 16; ++kt) {
        *(uint4*)&As[r * 40 + c8] = *(const uint4*)(Ag + kt * 32);
        *(uint4*)&Bs[r * 40 + c8] = *(const uint4*)(Bg + kt * 32);
        __syncthreads();
        bf16x8 af = *(const bf16x8*)&As[(w * 16 + lr) * 40 + lq * 8];
        bf16x8 b0 = *(const bf16x8*)&Bs[(0 * 16 + lr) * 40 + lq * 8];
        bf16x8 b1 = *(const bf16x8*)&Bs[(1 * 16 + lr) * 40 + lq * 8];
        bf16x8 b2 = *(const bf16x8*)&Bs[(2 * 16 + lr) * 40 + lq * 8];
        bf16x8 b3 = *(const bf16x8*)&Bs[(3 * 16 + lr) * 40 + lq * 8];
        acc0 = __builtin_amdgcn_mfma_f32_16x16x32_bf16(af, b0, acc0, 0, 0, 0);
        acc1 = __builtin_amdgcn_mfma_f32_16x16x32_bf16(af, b1, acc1, 0, 0, 0);
        acc2 = __builtin_amdgcn_mfma_f32_16x16x32_bf16(af, b2, acc2, 0, 0, 0);
        acc3 = __builtin_amdgcn_mfma_f32_16x16x32_bf16(af, b3, acc3, 0, 0, 0);
        __syncthreads();
    }

    f32x4 accs[4] = {acc0, acc1, acc2, acc3};
    #pragma unroll
    for (int nt = 0; nt < 4; ++nt) {
        const int v = bn * 64 + nt * 16 + lr;
        const float bo = bout[v];
        #pragma unroll
        for (int reg = 0; reg < 4; ++reg) {
            const int m = bm * 64 + w * 16 + lq * 4 + reg;
            if (m < TSZ * BSZ) {
                const int tt = m >> 5, bb = m & 31;
                out[(size_t)(bb * TSZ + tt) * VSZ + v] = accs[nt][reg] + bo;
            }
        }
    }
}

extern "C" void kernel_launch(void* const* d_in, const int* in_sizes, int n_in,
                              void* d_out, int out_size, void* d_ws, size_t ws_size,
                              hipStream_t stream) {
    const float* dec_h = (const float*)d_in[1];
    const float* dec_c = (const float*)d_in[2];
    const int*   tgt   = (const int*)d_in[3];
    const float* emb   = (const float*)d_in[4];
    const float* Wih   = (const float*)d_in[5];
    const float* Whh   = (const float*)d_in[6];
    const float* bihp  = (const float*)d_in[7];
    const float* bhhp  = (const float*)d_in[8];
    const float* Wout  = (const float*)d_in[9];
    const float* bout  = (const float*)d_in[10];
    float* out = (float*)d_out;
    float* ws  = (float*)d_ws;

    unsigned short* HTOP = (unsigned short*)(ws + WS_HTOP);
    unsigned short* WB   = (unsigned short*)(ws + WS_WB);

    // zero the p2p sync counters (graph-capture safe)
    hipMemsetAsync(ws + WS_CNT, 0, 1040, stream);

    // W_out -> bf16 (independent of the recurrence)
    convw_kernel<<<4096, 256, 0, stream>>>(Wout, WB);

    // MFMA ring-buffered p2p pipelined LSTM (cooperative launch for co-residency)
    void* args[] = { (void*)&dec_h, (void*)&dec_c, (void*)&tgt, (void*)&emb,
                     (void*)&Wih, (void*)&Whh, (void*)&bihp, (void*)&bhhp,
                     (void*)&ws, (void*)&out };
    hipLaunchCooperativeKernel(reinterpret_cast<void*>(lstm_kernel),
                               dim3(256), dim3(512), args, 0, stream);

    // batched output projection
    proj_kernel<<<dim3(VSZ / 64, MPAD / 64), 256, 0, stream>>>(HTOP, WB, bout, out);
}